// Round 1
// 1032.992 us; speedup vs baseline: 1.4508x; 1.4508x over previous
//
#include <hip/hip_runtime.h>
#include <hip/hip_bf16.h>

#define E_EDGES 262144
#define N_NODES 16384

typedef short bf16x8 __attribute__((ext_vector_type(8)));
typedef float f32x4 __attribute__((ext_vector_type(4)));

static __device__ __forceinline__ short f2bf(float f) {
    union { float f; unsigned u; } v; v.f = f;
    unsigned r = v.u + 0x7FFFu + ((v.u >> 16) & 1u);
    return (short)(r >> 16);
}
static __device__ __forceinline__ float bf2f(short s) {
    union { unsigned u; float f; } v;
    v.u = ((unsigned)(unsigned short)s) << 16;
    return v.f;
}

// ---------------- weight prep: bf16 transposed copies ----------------
__global__ void kprep(const float* __restrict__ Wk, const float* __restrict__ Wenv,
                      const float* __restrict__ Wmix, const float* __restrict__ Wsc,
                      short* __restrict__ WkT, short* __restrict__ WenvT,
                      short* __restrict__ WcatT) {
    int idx = blockIdx.x * 256 + threadIdx.x;
    if (idx < 65536) {
        int c = idx >> 7, k = idx & 127;
        WkT[idx] = f2bf(Wk[k * 512 + c]);
    } else if (idx < 65536 + 8192) {
        int o = idx - 65536;
        int c = o >> 7, k = o & 127;
        WenvT[o] = f2bf(Wenv[k * 64 + c]);
    } else {
        int o = idx - (65536 + 8192);
        int c = o / 96, k = o - c * 96;
        float v = 0.f;
        if (k < 80) v = (c < 128) ? Wmix[k * 128 + c] : Wsc[k * 128 + (c - 128)];
        WcatT[o] = f2bf(v);
    }
}

// ---------------- CSR build: histogram, scan, scatter ----------------
__global__ void khist(const int* __restrict__ ec, int* __restrict__ deg) {
    int e = blockIdx.x * 256 + threadIdx.x;
    atomicAdd(&deg[ec[e]], 1);
}

__global__ void kscan(const int* __restrict__ deg, int* __restrict__ offs,
                      int* __restrict__ cursor) {
    __shared__ int part[256];
    int t = threadIdx.x;
    int s = 0;
    for (int i = 0; i < 64; ++i) s += deg[t * 64 + i];
    part[t] = s;
    __syncthreads();
    if (t == 0) {
        int acc = 0;
        for (int i = 0; i < 256; ++i) { int v = part[i]; part[i] = acc; acc += v; }
        offs[N_NODES] = acc;
    }
    __syncthreads();
    int p = part[t];
    for (int i = 0; i < 64; ++i) {
        int idx = t * 64 + i;
        offs[idx] = p;
        cursor[idx] = p;
        p += deg[idx];
    }
}

__global__ void kscat(const int* __restrict__ ec, int* __restrict__ cursor,
                      int* __restrict__ csr) {
    int e = blockIdx.x * 256 + threadIdx.x;
    int p = atomicAdd(&cursor[ec[e]], 1);
    csr[p] = e;
}

// ---------------- Qn = node_invariants @ Wq  (N x 512, fp32) ----------------
__global__ void kqn(const float* __restrict__ ninv, const float* __restrict__ Wq,
                    float* __restrict__ Qn) {
    __shared__ float ni[8 * 68];
    int nBase = blockIdx.x * 8;
    int tid = threadIdx.x;
    for (int idx = tid; idx < 512; idx += 256) {
        int n = idx >> 6, j = idx & 63;
        ni[n * 68 + j] = ninv[(nBase + n) * 64 + j];
    }
    __syncthreads();
    float a0[8] = {0,0,0,0,0,0,0,0};
    float a1[8] = {0,0,0,0,0,0,0,0};
    for (int j = 0; j < 64; ++j) {
        float w0 = Wq[j * 512 + tid];
        float w1 = Wq[j * 512 + tid + 256];
#pragma unroll
        for (int n = 0; n < 8; ++n) {
            float s = ni[n * 68 + j];
            a0[n] += s * w0;
            a1[n] += s * w1;
        }
    }
#pragma unroll
    for (int n = 0; n < 8; ++n) {
        Qn[(nBase + n) * 512 + tid] = a0[n];
        Qn[(nBase + n) * 512 + tid + 256] = a1[n];
    }
}

// ---------------- main edge kernel: g (silu), logits -> z (NO atomics) ----------------
__launch_bounds__(256)
__global__ void kmain1(const float* __restrict__ sl, const int* __restrict__ ec,
                       const float* __restrict__ Qn, const short* __restrict__ WkT,
                       const short* __restrict__ WenvT, const float* __restrict__ benv,
                       float* __restrict__ zbuf, short* __restrict__ gbuf) {
    __shared__ short slb[16 * 136];
    __shared__ int cn[16];
    int tid = threadIdx.x;
    int eBase = blockIdx.x * 16;
    for (int idx = tid; idx < 2048; idx += 256) {
        int e = idx >> 7, j = idx & 127;
        slb[e * 136 + j] = f2bf(sl[(eBase + e) * 128 + j]);
    }
    if (tid < 16) cn[tid] = ec[eBase + tid];
    __syncthreads();

    int lane = tid & 63, wv = tid >> 6;
    int r = lane & 15, q = lane >> 4;

    bf16x8 af[4];
#pragma unroll
    for (int kk = 0; kk < 4; ++kk)
        af[kk] = *(const bf16x8*)&slb[r * 136 + kk * 32 + q * 8];

    // ---- g = silu(sl @ W_env + b_env), col tile per wave ----
    {
        f32x4 acc = {0.f, 0.f, 0.f, 0.f};
#pragma unroll
        for (int kk = 0; kk < 4; ++kk) {
            bf16x8 bb = *(const bf16x8*)&WenvT[(wv * 16 + r) * 128 + kk * 32 + q * 8];
            acc = __builtin_amdgcn_mfma_f32_16x16x32_bf16(af[kk], bb, acc, 0, 0, 0);
        }
        int gcol = wv * 16 + r;
        float bias = benv[gcol];
#pragma unroll
        for (int reg = 0; reg < 4; ++reg) {
            int e = q * 4 + reg;
            float x = acc[reg] + bias;
            float gv = x / (1.f + __expf(-x));
            gbuf[(eBase + e) * 64 + gcol] = f2bf(gv);
        }
    }

    // ---- logits -> z ----
    for (int mi = 0; mi < 8; ++mi) {
        int m = wv * 8 + mi;
        f32x4 acc = {0.f, 0.f, 0.f, 0.f};
#pragma unroll
        for (int kk = 0; kk < 4; ++kk) {
            bf16x8 bb = *(const bf16x8*)&WkT[(m * 16 + r) * 128 + kk * 32 + q * 8];
            acc = __builtin_amdgcn_mfma_f32_16x16x32_bf16(af[kk], bb, acc, 0, 0, 0);
        }
        float p[4];
#pragma unroll
        for (int reg = 0; reg < 4; ++reg) {
            int e = q * 4 + reg;
            float qv = Qn[cn[e] * 512 + m * 16 + r];
            p[reg] = acc[reg] * qv;
        }
#pragma unroll
        for (int off = 1; off < 16; off <<= 1) {
#pragma unroll
            for (int reg = 0; reg < 4; ++reg)
                p[reg] += __shfl_xor(p[reg], off, 16);
        }
        if (r == 0) {
#pragma unroll
            for (int reg = 0; reg < 4; ++reg) {
                int e = q * 4 + reg;
                float l = p[reg] * 0.25f;           // INV_SQRTD
                l = fminf(5.f, fmaxf(-5.f, l));     // clip
                zbuf[(eBase + e) * 32 + m] = __expf(l);
            }
        }
    }
}

// ---------------- node-centric aggregation: denom + env sum + SO3 LN ----------------
// One wave per node. Lane l: m = l>>1, half = l&1, owns components c0=m*4+half*2, c0+1.
// env[n,m,d] = (sum_e z*g*equiv) / (sum_e z)  -- normalization after the sum.
__launch_bounds__(256)
__global__ void kagg(const float* __restrict__ equiv, const float* __restrict__ zbuf,
                     const short* __restrict__ gbuf, const int* __restrict__ offs,
                     const int* __restrict__ csr, float* __restrict__ envn) {
    int tid = threadIdx.x;
    int wv = tid >> 6, lane = tid & 63;
    int node = blockIdx.x * 4 + wv;
    int m = lane >> 1, half = lane & 1;
    int c0 = m * 4 + half * 2;

    int start = offs[node], end = offs[node + 1];
    float d_acc = 0.f, a0 = 0.f, a1 = 0.f;
#pragma unroll 2
    for (int idx = start; idx < end; ++idx) {
        int e = csr[idx];
        float z = zbuf[e * 32 + m];
        short2 g2 = *(const short2*)&gbuf[e * 64 + 2 * m];
        float2 eq = *(const float2*)&equiv[(size_t)e * 128 + c0];
        float ga = half ? bf2f(g2.y) : bf2f(g2.x);   // d0 -> g0 ; d2 -> g1
        float gb = bf2f(g2.y);                        // d1,d3 -> g1
        d_acc += z;
        a0 += z * ga * eq.x;
        a1 += z * gb * eq.y;
    }
    float e0 = 0.f, e1 = 0.f;
    if (end > start) {
        float inv = 1.f / d_acc;
        e0 = a0 * inv;
        e1 = a1 * inv;
    }
    // SO3 LN: s0 over components m*4+0 (32 elems), s1 over m*4+{1,2,3} (96 elems)
    float p0 = half ? 0.f : e0 * e0;
    float p1 = half ? (e0 * e0 + e1 * e1) : e1 * e1;
#pragma unroll
    for (int off = 1; off < 64; off <<= 1) {
        p0 += __shfl_xor(p0, off, 64);
        p1 += __shfl_xor(p1, off, 64);
    }
    float i0 = rsqrtf(p0 * (1.f / 32.f) + 1e-6f);
    float i1 = rsqrtf(p1 * (1.f / 96.f) + 1e-6f);
    float o0 = half ? (e0 * i1) : (e0 * i0);
    float o1 = e1 * i1;
    float2 o; o.x = o0; o.y = o1;
    *(float2*)&envn[(size_t)node * 128 + c0] = o;
}

// ---------------- final: tp, per-edge LN, feats, mix|sc GEMM, outputs ----------------
__launch_bounds__(256)
__global__ void kfinal(const float* __restrict__ sl, const float* __restrict__ equiv,
                       const float* __restrict__ econd, const int* __restrict__ ec,
                       const float* __restrict__ envn, const short* __restrict__ WcatT,
                       const float* __restrict__ bmix, const float* __restrict__ bsc,
                       const float* __restrict__ ucp, float* __restrict__ out) {
    __shared__ float eqlds[16 * 132];
    __shared__ float envl[16 * 132];
    __shared__ float mixl[16 * 132];
    __shared__ float condl[16 * 16];
    __shared__ short featb[16 * 104];
    __shared__ int cn[16];

    int tid = threadIdx.x;
    int eBase = blockIdx.x * 16;
    if (tid < 16) cn[tid] = ec[eBase + tid];
    for (int idx = tid; idx < 2048; idx += 256) {
        int e = idx >> 7, j = idx & 127;
        eqlds[e * 132 + j] = equiv[(eBase + e) * 128 + j];
    }
    {
        int e = tid >> 4, j = tid & 15;
        condl[tid] = econd[(eBase + e) * 16 + j];
    }
    float uc = ucp[0];
    float c_old = rsqrtf(uc * uc + 1.f);
    float c_new = uc * c_old;
    __syncthreads();
    for (int idx = tid; idx < 2048; idx += 256) {
        int e = idx >> 7, j = idx & 127;
        envl[e * 132 + j] = envn[cn[e] * 128 + j];
    }
    __syncthreads();

    int e = tid >> 4, i = tid & 15;
    float tp[2][8];
    {
        float s0 = 0, s1 = 0, s2 = 0, s3 = 0;
#pragma unroll
        for (int t2 = 0; t2 < 2; ++t2) {
            int m = i * 2 + t2;
            float4 x = *(const float4*)&eqlds[e * 132 + m * 4];
            float4 y = *(const float4*)&envl[e * 132 + m * 4];
            tp[t2][0] = x.x * y.x;
            tp[t2][1] = x.x * y.y; tp[t2][2] = x.x * y.z; tp[t2][3] = x.x * y.w;
            tp[t2][4] = x.y * y.x; tp[t2][5] = x.z * y.x; tp[t2][6] = x.w * y.x;
            tp[t2][7] = (x.y * y.y + x.z * y.z + x.w * y.w) * 0.57735026919f;
            s0 += tp[t2][0] * tp[t2][0];
            s1 += tp[t2][1] * tp[t2][1] + tp[t2][2] * tp[t2][2] + tp[t2][3] * tp[t2][3];
            s2 += tp[t2][4] * tp[t2][4] + tp[t2][5] * tp[t2][5] + tp[t2][6] * tp[t2][6];
            s3 += tp[t2][7] * tp[t2][7];
        }
#pragma unroll
        for (int off = 1; off < 16; off <<= 1) {
            s0 += __shfl_xor(s0, off, 16);
            s1 += __shfl_xor(s1, off, 16);
            s2 += __shfl_xor(s2, off, 16);
            s3 += __shfl_xor(s3, off, 16);
        }
        float i0 = rsqrtf(s0 * (1.f / 32.f) + 1e-6f);
        float i1 = rsqrtf(s1 * (1.f / 96.f) + 1e-6f);
        float i2 = rsqrtf(s2 * (1.f / 96.f) + 1e-6f);
        float i3 = rsqrtf(s3 * (1.f / 32.f) + 1e-6f);
#pragma unroll
        for (int t2 = 0; t2 < 2; ++t2) {
            tp[t2][0] *= i0;
            tp[t2][1] *= i1; tp[t2][2] *= i1; tp[t2][3] *= i1;
            tp[t2][4] *= i2; tp[t2][5] *= i2; tp[t2][6] *= i2;
            tp[t2][7] *= i3;
            int m = i * 2 + t2;
            featb[e * 104 + m] = f2bf(tp[t2][0]);
            featb[e * 104 + 32 + m] = f2bf(tp[t2][7]);
        }
        featb[e * 104 + 64 + i] = f2bf(condl[e * 16 + i]);
        featb[e * 104 + 80 + i] = 0;
    }
    __syncthreads();

    int lane = tid & 63, wv = tid >> 6;
    int r = lane & 15, q = lane >> 4;
    bf16x8 af[3];
#pragma unroll
    for (int kk = 0; kk < 3; ++kk)
        af[kk] = *(const bf16x8*)&featb[r * 104 + kk * 32 + q * 8];
#pragma unroll
    for (int ct4 = 0; ct4 < 4; ++ct4) {
        int ct = wv * 4 + ct4;
        f32x4 acc = {0.f, 0.f, 0.f, 0.f};
#pragma unroll
        for (int kk = 0; kk < 3; ++kk) {
            bf16x8 bb = *(const bf16x8*)&WcatT[(ct * 16 + r) * 96 + kk * 32 + q * 8];
            acc = __builtin_amdgcn_mfma_f32_16x16x32_bf16(af[kk], bb, acc, 0, 0, 0);
        }
        int colg = ct * 16 + r;
        if (colg < 128) {
            float bias = bmix[colg];
#pragma unroll
            for (int reg = 0; reg < 4; ++reg) {
                int ee = q * 4 + reg;
                mixl[ee * 132 + colg] = acc[reg] + bias;
            }
        } else {
            int j = colg - 128;
            float bias = bsc[j];
#pragma unroll
            for (int reg = 0; reg < 4; ++reg) {
                int ee = q * 4 + reg;
                int ge = eBase + ee;
                out[ge * 128 + j] = c_old * sl[ge * 128 + j] + c_new * (acc[reg] + bias);
            }
        }
    }
    __syncthreads();

    float* outeq = out + (size_t)E_EDGES * 128;
#pragma unroll
    for (int t2 = 0; t2 < 2; ++t2) {
        int m = i * 2 + t2;
        float4 mx = *(const float4*)&mixl[e * 132 + m * 4];
        float4 eq = *(const float4*)&eqlds[e * 132 + m * 4];
        float4 o;
        o.x = c_old * eq.x + c_new * (mx.x * tp[t2][0] + mx.y * tp[t2][7]);
        o.y = c_old * eq.y + c_new * (mx.z * tp[t2][1] + mx.w * tp[t2][4]);
        o.z = c_old * eq.z + c_new * (mx.z * tp[t2][2] + mx.w * tp[t2][5]);
        o.w = c_old * eq.w + c_new * (mx.z * tp[t2][3] + mx.w * tp[t2][6]);
        *(float4*)&outeq[(size_t)(eBase + e) * 128 + m * 4] = o;
    }
}

extern "C" void kernel_launch(void* const* d_in, const int* in_sizes, int n_in,
                              void* d_out, int out_size, void* d_ws, size_t ws_size,
                              hipStream_t stream) {
    const float* sl    = (const float*)d_in[0];
    const float* eqv   = (const float*)d_in[1];
    const float* ninv  = (const float*)d_in[2];
    const float* econd = (const float*)d_in[3];
    const float* uc    = (const float*)d_in[4];
    const float* Wenv  = (const float*)d_in[5];
    const float* benv  = (const float*)d_in[6];
    const float* Wq    = (const float*)d_in[7];
    const float* Wk    = (const float*)d_in[8];
    const float* Wmix  = (const float*)d_in[9];
    const float* bmix  = (const float*)d_in[10];
    const float* Wsc   = (const float*)d_in[11];
    const float* bsc   = (const float*)d_in[12];
    const int*   ec    = (const int*)d_in[13];
    float* out = (float*)d_out;

    float* ws = (float*)d_ws;
    float* Qn    = ws;                                    // N*512 f32
    float* zbuf  = Qn + (size_t)N_NODES * 512;            // E*32 f32
    float* envn  = zbuf + (size_t)E_EDGES * 32;           // N*128 f32
    short* gbuf  = (short*)(envn + (size_t)N_NODES * 128); // E*64 bf16
    short* WkT   = gbuf + (size_t)E_EDGES * 64;           // 512*128
    short* WenvT = WkT + 65536;                           // 64*128
    short* WcatT = WenvT + 8192;                          // 256*96
    int*   deg    = (int*)(WcatT + 24576);                // N
    int*   offs   = deg + N_NODES;                        // N+1
    int*   cursor = offs + N_NODES + 1;                   // N
    int*   csr    = cursor + N_NODES;                     // E

    hipMemsetAsync(deg, 0, (size_t)N_NODES * sizeof(int), stream);

    kprep<<<384, 256, 0, stream>>>(Wk, Wenv, Wmix, Wsc, WkT, WenvT, WcatT);
    khist<<<E_EDGES / 256, 256, 0, stream>>>(ec, deg);
    kscan<<<1, 256, 0, stream>>>(deg, offs, cursor);
    kscat<<<E_EDGES / 256, 256, 0, stream>>>(ec, cursor, csr);
    kqn<<<N_NODES / 8, 256, 0, stream>>>(ninv, Wq, Qn);
    kmain1<<<E_EDGES / 16, 256, 0, stream>>>(sl, ec, Qn, WkT, WenvT, benv, zbuf, gbuf);
    kagg<<<N_NODES / 4, 256, 0, stream>>>(eqv, zbuf, gbuf, offs, csr, envn);
    kfinal<<<E_EDGES / 16, 256, 0, stream>>>(sl, eqv, econd, ec, envn, WcatT, bmix, bsc, uc, out);
}

// Round 2
// 975.048 us; speedup vs baseline: 1.5370x; 1.0594x over previous
//
#include <hip/hip_runtime.h>
#include <hip/hip_bf16.h>

#define E_EDGES 262144
#define N_NODES 16384

typedef short bf16x8 __attribute__((ext_vector_type(8)));
typedef float f32x4 __attribute__((ext_vector_type(4)));

static __device__ __forceinline__ short f2bf(float f) {
    union { float f; unsigned u; } v; v.f = f;
    unsigned r = v.u + 0x7FFFu + ((v.u >> 16) & 1u);
    return (short)(r >> 16);
}
static __device__ __forceinline__ float bf2f(short s) {
    union { unsigned u; float f; } v;
    v.u = ((unsigned)(unsigned short)s) << 16;
    return v.f;
}

// ---------------- weight prep: bf16 transposed copies ----------------
__global__ void kprep(const float* __restrict__ Wk, const float* __restrict__ Wenv,
                      const float* __restrict__ Wmix, const float* __restrict__ Wsc,
                      short* __restrict__ WkT, short* __restrict__ WenvT,
                      short* __restrict__ WcatT) {
    int idx = blockIdx.x * 256 + threadIdx.x;
    if (idx < 65536) {
        int c = idx >> 7, k = idx & 127;
        WkT[idx] = f2bf(Wk[k * 512 + c]);
    } else if (idx < 65536 + 8192) {
        int o = idx - 65536;
        int c = o >> 7, k = o & 127;
        WenvT[o] = f2bf(Wenv[k * 64 + c]);
    } else {
        int o = idx - (65536 + 8192);
        int c = o / 96, k = o - c * 96;
        float v = 0.f;
        if (k < 80) v = (c < 128) ? Wmix[k * 128 + c] : Wsc[k * 128 + (c - 128)];
        WcatT[o] = f2bf(v);
    }
}

// ---------------- CSR build: histogram, scan, scatter ----------------
__global__ void khist(const int* __restrict__ ec, int* __restrict__ deg) {
    int e = blockIdx.x * 256 + threadIdx.x;
    atomicAdd(&deg[ec[e]], 1);
}

__global__ void kscan(const int* __restrict__ deg, int* __restrict__ offs,
                      int* __restrict__ cursor) {
    __shared__ int part[256];
    int t = threadIdx.x;
    int s = 0;
    for (int i = 0; i < 64; ++i) s += deg[t * 64 + i];
    part[t] = s;
    __syncthreads();
    if (t == 0) {
        int acc = 0;
        for (int i = 0; i < 256; ++i) { int v = part[i]; part[i] = acc; acc += v; }
        offs[N_NODES] = acc;
    }
    __syncthreads();
    int p = part[t];
    for (int i = 0; i < 64; ++i) {
        int idx = t * 64 + i;
        offs[idx] = p;
        cursor[idx] = p;
        p += deg[idx];
    }
}

__global__ void kscat(const int* __restrict__ ec, int* __restrict__ cursor,
                      int* __restrict__ csr) {
    int e = blockIdx.x * 256 + threadIdx.x;
    int p = atomicAdd(&cursor[ec[e]], 1);
    csr[p] = e;
}

// ---------------- Qnb = bf16(node_invariants @ Wq)  (N x 512) ----------------
__global__ void kqn(const float* __restrict__ ninv, const float* __restrict__ Wq,
                    unsigned short* __restrict__ Qnb) {
    __shared__ float ni[8 * 68];
    int nBase = blockIdx.x * 8;
    int tid = threadIdx.x;
    for (int idx = tid; idx < 512; idx += 256) {
        int n = idx >> 6, j = idx & 63;
        ni[n * 68 + j] = ninv[(nBase + n) * 64 + j];
    }
    __syncthreads();
    float a0[8] = {0,0,0,0,0,0,0,0};
    float a1[8] = {0,0,0,0,0,0,0,0};
    for (int j = 0; j < 64; ++j) {
        float w0 = Wq[j * 512 + tid];
        float w1 = Wq[j * 512 + tid + 256];
#pragma unroll
        for (int n = 0; n < 8; ++n) {
            float s = ni[n * 68 + j];
            a0[n] += s * w0;
            a1[n] += s * w1;
        }
    }
#pragma unroll
    for (int n = 0; n < 8; ++n) {
        Qnb[(nBase + n) * 512 + tid] = (unsigned short)f2bf(a0[n]);
        Qnb[(nBase + n) * 512 + tid + 256] = (unsigned short)f2bf(a1[n]);
    }
}

// ---------------- main edge kernel (CSR-ordered): g (silu), logits -> z ----------------
// Block handles csr positions [blockIdx*16, +16). Edges within a block mostly share
// the same center node -> Qnb row gathers become L1 hits. zbuf/gbuf indexed by POS.
__launch_bounds__(256)
__global__ void kmain1(const float* __restrict__ sl, const int* __restrict__ ec,
                       const int* __restrict__ csr,
                       const unsigned short* __restrict__ Qnb, const short* __restrict__ WkT,
                       const short* __restrict__ WenvT, const float* __restrict__ benv,
                       float* __restrict__ zbuf, short* __restrict__ gbuf) {
    __shared__ short slb[16 * 136];
    __shared__ int cn[16];
    int tid = threadIdx.x;
    int pBase = blockIdx.x * 16;
    if (tid < 16) cn[tid] = ec[csr[pBase + tid]];
    // staged sl load: edge id re-read per strip (broadcast within 32 lanes, L1 hit)
    for (int idx = tid; idx < 512; idx += 256) {
        int e = idx >> 5, j4 = idx & 31;
        int ge = csr[pBase + e];
        float4 v = *(const float4*)&sl[(size_t)ge * 128 + j4 * 4];
        short4 s4;
        s4.x = f2bf(v.x); s4.y = f2bf(v.y); s4.z = f2bf(v.z); s4.w = f2bf(v.w);
        *(short4*)&slb[e * 136 + j4 * 4] = s4;
    }
    __syncthreads();

    int lane = tid & 63, wv = tid >> 6;
    int r = lane & 15, q = lane >> 4;

    bf16x8 af[4];
#pragma unroll
    for (int kk = 0; kk < 4; ++kk)
        af[kk] = *(const bf16x8*)&slb[r * 136 + kk * 32 + q * 8];

    // ---- g = silu(sl @ W_env + b_env), col tile per wave ----
    {
        f32x4 acc = {0.f, 0.f, 0.f, 0.f};
#pragma unroll
        for (int kk = 0; kk < 4; ++kk) {
            bf16x8 bb = *(const bf16x8*)&WenvT[(wv * 16 + r) * 128 + kk * 32 + q * 8];
            acc = __builtin_amdgcn_mfma_f32_16x16x32_bf16(af[kk], bb, acc, 0, 0, 0);
        }
        int gcol = wv * 16 + r;
        float bias = benv[gcol];
#pragma unroll
        for (int reg = 0; reg < 4; ++reg) {
            int e = q * 4 + reg;
            float x = acc[reg] + bias;
            float gv = x / (1.f + __expf(-x));
            gbuf[(pBase + e) * 64 + gcol] = f2bf(gv);
        }
    }

    // ---- logits -> z ----
    for (int mi = 0; mi < 8; ++mi) {
        int m = wv * 8 + mi;
        f32x4 acc = {0.f, 0.f, 0.f, 0.f};
#pragma unroll
        for (int kk = 0; kk < 4; ++kk) {
            bf16x8 bb = *(const bf16x8*)&WkT[(m * 16 + r) * 128 + kk * 32 + q * 8];
            acc = __builtin_amdgcn_mfma_f32_16x16x32_bf16(af[kk], bb, acc, 0, 0, 0);
        }
        float p[4];
#pragma unroll
        for (int reg = 0; reg < 4; ++reg) {
            int e = q * 4 + reg;
            float qv = bf2f((short)Qnb[(size_t)cn[e] * 512 + m * 16 + r]);
            p[reg] = acc[reg] * qv;
        }
#pragma unroll
        for (int off = 1; off < 16; off <<= 1) {
#pragma unroll
            for (int reg = 0; reg < 4; ++reg)
                p[reg] += __shfl_xor(p[reg], off, 16);
        }
        if (r == 0) {
#pragma unroll
            for (int reg = 0; reg < 4; ++reg) {
                int e = q * 4 + reg;
                float l = p[reg] * 0.25f;           // INV_SQRTD
                l = fminf(5.f, fmaxf(-5.f, l));     // clip
                zbuf[(pBase + e) * 32 + m] = __expf(l);
            }
        }
    }
}

// ---------------- node-centric aggregation: denom + env sum + SO3 LN ----------------
// zbuf/gbuf are CSR-position-indexed -> fully sequential reads here.
__launch_bounds__(256)
__global__ void kagg(const float* __restrict__ equiv, const float* __restrict__ zbuf,
                     const short* __restrict__ gbuf, const int* __restrict__ offs,
                     const int* __restrict__ csr, float* __restrict__ envn) {
    int tid = threadIdx.x;
    int wv = tid >> 6, lane = tid & 63;
    int node = blockIdx.x * 4 + wv;
    int m = lane >> 1, half = lane & 1;
    int c0 = m * 4 + half * 2;

    int start = offs[node], end = offs[node + 1];
    float d_acc = 0.f, a0 = 0.f, a1 = 0.f;
#pragma unroll 2
    for (int idx = start; idx < end; ++idx) {
        int e = csr[idx];
        float z = zbuf[idx * 32 + m];
        short2 g2 = *(const short2*)&gbuf[idx * 64 + 2 * m];
        float2 eq = *(const float2*)&equiv[(size_t)e * 128 + c0];
        float ga = half ? bf2f(g2.y) : bf2f(g2.x);
        float gb = bf2f(g2.y);
        d_acc += z;
        a0 += z * ga * eq.x;
        a1 += z * gb * eq.y;
    }
    float e0 = 0.f, e1 = 0.f;
    if (end > start) {
        float inv = 1.f / d_acc;
        e0 = a0 * inv;
        e1 = a1 * inv;
    }
    float p0 = half ? 0.f : e0 * e0;
    float p1 = half ? (e0 * e0 + e1 * e1) : e1 * e1;
#pragma unroll
    for (int off = 1; off < 64; off <<= 1) {
        p0 += __shfl_xor(p0, off, 64);
        p1 += __shfl_xor(p1, off, 64);
    }
    float i0 = rsqrtf(p0 * (1.f / 32.f) + 1e-6f);
    float i1 = rsqrtf(p1 * (1.f / 96.f) + 1e-6f);
    float o0 = half ? (e0 * i1) : (e0 * i0);
    float o1 = e1 * i1;
    float2 o; o.x = o0; o.y = o1;
    *(float2*)&envn[(size_t)node * 128 + c0] = o;
}

// ---------------- final: tp, per-edge LN, feats, mix|sc GEMM, outputs ----------------
__launch_bounds__(256)
__global__ void kfinal(const float* __restrict__ sl, const float* __restrict__ equiv,
                       const float* __restrict__ econd, const int* __restrict__ ec,
                       const float* __restrict__ envn, const short* __restrict__ WcatT,
                       const float* __restrict__ bmix, const float* __restrict__ bsc,
                       const float* __restrict__ ucp, float* __restrict__ out) {
    __shared__ float eqlds[16 * 132];
    __shared__ float envl[16 * 132];
    __shared__ float mixl[16 * 132];
    __shared__ float condl[16 * 16];
    __shared__ short featb[16 * 104];
    __shared__ int cn[16];

    int tid = threadIdx.x;
    int eBase = blockIdx.x * 16;
    if (tid < 16) cn[tid] = ec[eBase + tid];
    for (int idx = tid; idx < 512; idx += 256) {
        int e = idx >> 5, j4 = idx & 31;
        *(float4*)&eqlds[e * 132 + j4 * 4] =
            *(const float4*)&equiv[(size_t)(eBase + e) * 128 + j4 * 4];
    }
    {
        int e = tid >> 4, j = tid & 15;
        condl[tid] = econd[(eBase + e) * 16 + j];
    }
    float uc = ucp[0];
    float c_old = rsqrtf(uc * uc + 1.f);
    float c_new = uc * c_old;
    __syncthreads();
    for (int idx = tid; idx < 512; idx += 256) {
        int e = idx >> 5, j4 = idx & 31;
        *(float4*)&envl[e * 132 + j4 * 4] =
            *(const float4*)&envn[(size_t)cn[e] * 128 + j4 * 4];
    }
    __syncthreads();

    int e = tid >> 4, i = tid & 15;
    float tp[2][8];
    {
        float s0 = 0, s1 = 0, s2 = 0, s3 = 0;
#pragma unroll
        for (int t2 = 0; t2 < 2; ++t2) {
            int m = i * 2 + t2;
            float4 x = *(const float4*)&eqlds[e * 132 + m * 4];
            float4 y = *(const float4*)&envl[e * 132 + m * 4];
            tp[t2][0] = x.x * y.x;
            tp[t2][1] = x.x * y.y; tp[t2][2] = x.x * y.z; tp[t2][3] = x.x * y.w;
            tp[t2][4] = x.y * y.x; tp[t2][5] = x.z * y.x; tp[t2][6] = x.w * y.x;
            tp[t2][7] = (x.y * y.y + x.z * y.z + x.w * y.w) * 0.57735026919f;
            s0 += tp[t2][0] * tp[t2][0];
            s1 += tp[t2][1] * tp[t2][1] + tp[t2][2] * tp[t2][2] + tp[t2][3] * tp[t2][3];
            s2 += tp[t2][4] * tp[t2][4] + tp[t2][5] * tp[t2][5] + tp[t2][6] * tp[t2][6];
            s3 += tp[t2][7] * tp[t2][7];
        }
#pragma unroll
        for (int off = 1; off < 16; off <<= 1) {
            s0 += __shfl_xor(s0, off, 16);
            s1 += __shfl_xor(s1, off, 16);
            s2 += __shfl_xor(s2, off, 16);
            s3 += __shfl_xor(s3, off, 16);
        }
        float i0 = rsqrtf(s0 * (1.f / 32.f) + 1e-6f);
        float i1 = rsqrtf(s1 * (1.f / 96.f) + 1e-6f);
        float i2 = rsqrtf(s2 * (1.f / 96.f) + 1e-6f);
        float i3 = rsqrtf(s3 * (1.f / 32.f) + 1e-6f);
#pragma unroll
        for (int t2 = 0; t2 < 2; ++t2) {
            tp[t2][0] *= i0;
            tp[t2][1] *= i1; tp[t2][2] *= i1; tp[t2][3] *= i1;
            tp[t2][4] *= i2; tp[t2][5] *= i2; tp[t2][6] *= i2;
            tp[t2][7] *= i3;
            int m = i * 2 + t2;
            featb[e * 104 + m] = f2bf(tp[t2][0]);
            featb[e * 104 + 32 + m] = f2bf(tp[t2][7]);
        }
        featb[e * 104 + 64 + i] = f2bf(condl[e * 16 + i]);
        featb[e * 104 + 80 + i] = 0;
    }
    __syncthreads();

    int lane = tid & 63, wv = tid >> 6;
    int r = lane & 15, q = lane >> 4;
    bf16x8 af[3];
#pragma unroll
    for (int kk = 0; kk < 3; ++kk)
        af[kk] = *(const bf16x8*)&featb[r * 104 + kk * 32 + q * 8];
#pragma unroll
    for (int ct4 = 0; ct4 < 4; ++ct4) {
        int ct = wv * 4 + ct4;
        f32x4 acc = {0.f, 0.f, 0.f, 0.f};
#pragma unroll
        for (int kk = 0; kk < 3; ++kk) {
            bf16x8 bb = *(const bf16x8*)&WcatT[(ct * 16 + r) * 96 + kk * 32 + q * 8];
            acc = __builtin_amdgcn_mfma_f32_16x16x32_bf16(af[kk], bb, acc, 0, 0, 0);
        }
        int colg = ct * 16 + r;
        if (colg < 128) {
            float bias = bmix[colg];
#pragma unroll
            for (int reg = 0; reg < 4; ++reg) {
                int ee = q * 4 + reg;
                mixl[ee * 132 + colg] = acc[reg] + bias;
            }
        } else {
            int j = colg - 128;
            float bias = bsc[j];
#pragma unroll
            for (int reg = 0; reg < 4; ++reg) {
                int ee = q * 4 + reg;
                int ge = eBase + ee;
                out[ge * 128 + j] = c_old * sl[ge * 128 + j] + c_new * (acc[reg] + bias);
            }
        }
    }
    __syncthreads();

    float* outeq = out + (size_t)E_EDGES * 128;
#pragma unroll
    for (int t2 = 0; t2 < 2; ++t2) {
        int m = i * 2 + t2;
        float4 mx = *(const float4*)&mixl[e * 132 + m * 4];
        float4 eq = *(const float4*)&eqlds[e * 132 + m * 4];
        float4 o;
        o.x = c_old * eq.x + c_new * (mx.x * tp[t2][0] + mx.y * tp[t2][7]);
        o.y = c_old * eq.y + c_new * (mx.z * tp[t2][1] + mx.w * tp[t2][4]);
        o.z = c_old * eq.z + c_new * (mx.z * tp[t2][2] + mx.w * tp[t2][5]);
        o.w = c_old * eq.w + c_new * (mx.z * tp[t2][3] + mx.w * tp[t2][6]);
        *(float4*)&outeq[(size_t)(eBase + e) * 128 + m * 4] = o;
    }
}

extern "C" void kernel_launch(void* const* d_in, const int* in_sizes, int n_in,
                              void* d_out, int out_size, void* d_ws, size_t ws_size,
                              hipStream_t stream) {
    const float* sl    = (const float*)d_in[0];
    const float* eqv   = (const float*)d_in[1];
    const float* ninv  = (const float*)d_in[2];
    const float* econd = (const float*)d_in[3];
    const float* uc    = (const float*)d_in[4];
    const float* Wenv  = (const float*)d_in[5];
    const float* benv  = (const float*)d_in[6];
    const float* Wq    = (const float*)d_in[7];
    const float* Wk    = (const float*)d_in[8];
    const float* Wmix  = (const float*)d_in[9];
    const float* bmix  = (const float*)d_in[10];
    const float* Wsc   = (const float*)d_in[11];
    const float* bsc   = (const float*)d_in[12];
    const int*   ec    = (const int*)d_in[13];
    float* out = (float*)d_out;

    float* ws = (float*)d_ws;
    unsigned short* Qnb = (unsigned short*)ws;               // N*512 bf16
    float* zbuf  = (float*)(Qnb + (size_t)N_NODES * 512);    // E*32 f32 (csr-pos indexed)
    float* envn  = zbuf + (size_t)E_EDGES * 32;              // N*128 f32
    short* gbuf  = (short*)(envn + (size_t)N_NODES * 128);   // E*64 bf16 (csr-pos indexed)
    short* WkT   = gbuf + (size_t)E_EDGES * 64;              // 512*128
    short* WenvT = WkT + 65536;                              // 64*128
    short* WcatT = WenvT + 8192;                             // 256*96
    int*   deg    = (int*)(WcatT + 24576);                   // N
    int*   offs   = deg + N_NODES;                           // N+1
    int*   cursor = offs + N_NODES + 1;                      // N
    int*   csr    = cursor + N_NODES;                        // E

    hipMemsetAsync(deg, 0, (size_t)N_NODES * sizeof(int), stream);

    kprep<<<384, 256, 0, stream>>>(Wk, Wenv, Wmix, Wsc, WkT, WenvT, WcatT);
    khist<<<E_EDGES / 256, 256, 0, stream>>>(ec, deg);
    kscan<<<1, 256, 0, stream>>>(deg, offs, cursor);
    kscat<<<E_EDGES / 256, 256, 0, stream>>>(ec, cursor, csr);
    kqn<<<N_NODES / 8, 256, 0, stream>>>(ninv, Wq, Qnb);
    kmain1<<<E_EDGES / 16, 256, 0, stream>>>(sl, ec, csr, Qnb, WkT, WenvT, benv, zbuf, gbuf);
    kagg<<<N_NODES / 4, 256, 0, stream>>>(eqv, zbuf, gbuf, offs, csr, envn);
    kfinal<<<E_EDGES / 16, 256, 0, stream>>>(sl, eqv, econd, ec, envn, WcatT, bmix, bsc, uc, out);
}

// Round 3
// 862.466 us; speedup vs baseline: 1.7377x; 1.1305x over previous
//
#include <hip/hip_runtime.h>
#include <hip/hip_bf16.h>

#define E_EDGES 262144
#define N_NODES 16384

typedef short bf16x8 __attribute__((ext_vector_type(8)));
typedef float f32x4 __attribute__((ext_vector_type(4)));

static __device__ __forceinline__ short f2bf(float f) {
    union { float f; unsigned u; } v; v.f = f;
    unsigned r = v.u + 0x7FFFu + ((v.u >> 16) & 1u);
    return (short)(r >> 16);
}
static __device__ __forceinline__ float bf2f(short s) {
    union { unsigned u; float f; } v;
    v.u = ((unsigned)(unsigned short)s) << 16;
    return v.f;
}

// ---------------- weight prep: bf16 transposed copies ----------------
// WenvT[c*128+k] = W_env[k*64+c]             (64 x 128)
// WcatT[c*96+k]  = [W_mix | W_sc][k][c]      (256 x 96, k>=80 zero)
// WkB[m][c][dp]  = dp<16 ? Wk[c*512+m*16+dp] : 0   (32 x 128 x 32, K-padded)
__global__ void kprep(const float* __restrict__ Wk, const float* __restrict__ Wenv,
                      const float* __restrict__ Wmix, const float* __restrict__ Wsc,
                      short* __restrict__ WenvT, short* __restrict__ WcatT,
                      short* __restrict__ WkB) {
    int idx = blockIdx.x * 256 + threadIdx.x;
    if (idx < 8192) {
        int c = idx >> 7, k = idx & 127;
        WenvT[idx] = f2bf(Wenv[k * 64 + c]);
    } else if (idx < 8192 + 24576) {
        int o = idx - 8192;
        int c = o / 96, k = o - c * 96;
        float v = 0.f;
        if (k < 80) v = (c < 128) ? Wmix[k * 128 + c] : Wsc[k * 128 + (c - 128)];
        WcatT[o] = f2bf(v);
    } else {
        int o = idx - 32768;
        int m = o >> 12, rest = o & 4095;
        int c = rest >> 5, dp = rest & 31;
        WkB[o] = (dp < 16) ? f2bf(Wk[c * 512 + m * 16 + dp]) : (short)0;
    }
}

// ---------------- CSR build: histogram, scan, scatter ----------------
__global__ void khist(const int* __restrict__ ec, int* __restrict__ deg) {
    int e = blockIdx.x * 256 + threadIdx.x;
    atomicAdd(&deg[ec[e]], 1);
}

__global__ void kscan(const int* __restrict__ deg, int* __restrict__ offs,
                      int* __restrict__ cursor) {
    __shared__ int part[256];
    int t = threadIdx.x;
    int s = 0;
    for (int i = 0; i < 64; ++i) s += deg[t * 64 + i];
    part[t] = s;
    __syncthreads();
    if (t == 0) {
        int acc = 0;
        for (int i = 0; i < 256; ++i) { int v = part[i]; part[i] = acc; acc += v; }
        offs[N_NODES] = acc;
    }
    __syncthreads();
    int p = part[t];
    for (int i = 0; i < 64; ++i) {
        int idx = t * 64 + i;
        offs[idx] = p;
        cursor[idx] = p;
        p += deg[idx];
    }
}

__global__ void kscat(const int* __restrict__ ec, int* __restrict__ cursor,
                      int* __restrict__ csr) {
    int e = blockIdx.x * 256 + threadIdx.x;
    int p = atomicAdd(&cursor[ec[e]], 1);
    csr[p] = e;
}

// ---------------- Qn = node_invariants @ Wq  (N x 512, fp32) ----------------
__global__ void kqn(const float* __restrict__ ninv, const float* __restrict__ Wq,
                    float* __restrict__ Qn) {
    __shared__ float ni[8 * 68];
    int nBase = blockIdx.x * 8;
    int tid = threadIdx.x;
    for (int idx = tid; idx < 512; idx += 256) {
        int n = idx >> 6, j = idx & 63;
        ni[n * 68 + j] = ninv[(nBase + n) * 64 + j];
    }
    __syncthreads();
    float a0[8] = {0,0,0,0,0,0,0,0};
    float a1[8] = {0,0,0,0,0,0,0,0};
    for (int j = 0; j < 64; ++j) {
        float w0 = Wq[j * 512 + tid];
        float w1 = Wq[j * 512 + tid + 256];
#pragma unroll
        for (int n = 0; n < 8; ++n) {
            float s = ni[n * 68 + j];
            a0[n] += s * w0;
            a1[n] += s * w1;
        }
    }
#pragma unroll
    for (int n = 0; n < 8; ++n) {
        Qn[(nBase + n) * 512 + tid] = a0[n];
        Qn[(nBase + n) * 512 + tid + 256] = a1[n];
    }
}

// ---------------- kV: VT[nloc][m][c] = bf16( sum_d Wk[c,m*16+d] * Q[n,m*16+d] ) ----
// 16 nodes per block, wave w handles m = w*8..w*8+7. Zero-padded K=32 MFMA
// (WkB rows have zeros for d>=16; A re-reads d 0..15 there, products vanish).
__launch_bounds__(256)
__global__ void kV(const float* __restrict__ Qn, const short* __restrict__ WkB,
                   short* __restrict__ VT, int nb0) {
    int tid = threadIdx.x;
    int w = tid >> 6, lane = tid & 63;
    int r = lane & 15, q = lane >> 4;
    int nbl = blockIdx.x * 16;
#pragma unroll
    for (int mi = 0; mi < 8; ++mi) {
        int m = w * 8 + mi;
        const float* qp = &Qn[(size_t)(nb0 + nbl + r) * 512 + m * 16 + (q & 1) * 8];
        float4 qa = *(const float4*)qp;
        float4 qb = *(const float4*)(qp + 4);
        bf16x8 af;
        af[0] = f2bf(qa.x); af[1] = f2bf(qa.y); af[2] = f2bf(qa.z); af[3] = f2bf(qa.w);
        af[4] = f2bf(qb.x); af[5] = f2bf(qb.y); af[6] = f2bf(qb.z); af[7] = f2bf(qb.w);
#pragma unroll
        for (int ct = 0; ct < 8; ++ct) {
            bf16x8 bb = *(const bf16x8*)&WkB[(m * 128 + ct * 16 + r) * 32 + q * 8];
            f32x4 acc = {0.f, 0.f, 0.f, 0.f};
            acc = __builtin_amdgcn_mfma_f32_16x16x32_bf16(af, bb, acc, 0, 0, 0);
#pragma unroll
            for (int reg = 0; reg < 4; ++reg) {
                VT[(size_t)(nbl + q * 4 + reg) * 4096 + m * 128 + ct * 16 + r] =
                    f2bf(acc[reg]);
            }
        }
    }
}

// ---------------- kmain2: per-node fused logits/g/attn-aggregate/LN ----------------
// One wave per node. Loops the node's CSR edges in chunks of 16.
// Per chunk: stage sl->bf16 LDS (per-wave, no barriers), 8 MFMA -> logits (e,m),
// 16 MFMA -> g, accumulate denom + sum z*g*equiv in registers. End: q-reduce,
// normalize, SO3 LN, write envn.
__launch_bounds__(256)
__global__ void kmain2(const float* __restrict__ sl, const float* __restrict__ equiv,
                       const int* __restrict__ csr, const int* __restrict__ offs,
                       const short* __restrict__ VT, const short* __restrict__ WenvT,
                       const float* __restrict__ benv, float* __restrict__ envn,
                       int nb0) {
    __shared__ short slb[4][16 * 136];
    __shared__ short glds[4][16 * 68];
    int tid = threadIdx.x;
    int w = tid >> 6, lane = tid & 63;
    int r = lane & 15, q = lane >> 4;
    int node = nb0 + blockIdx.x * 4 + w;
    int start = offs[node], end = offs[node + 1];
    if (start >= end) return;   // no barriers in this kernel -> per-wave return is safe

    // logits B-frags: VT row m = ct*16+r, k = kk*32+q*8 (loaded once per node)
    bf16x8 vb[2][4];
    const short* vtn = VT + (size_t)(node - nb0) * 4096;
#pragma unroll
    for (int ct = 0; ct < 2; ++ct)
#pragma unroll
        for (int kk = 0; kk < 4; ++kk)
            vb[ct][kk] = *(const bf16x8*)&vtn[(ct * 16 + r) * 128 + kk * 32 + q * 8];
    float bias[4];
#pragma unroll
    for (int g4 = 0; g4 < 4; ++g4) bias[g4] = benv[g4 * 16 + r];

    float facc[2][4] = {{0,0,0,0},{0,0,0,0}};
    float dsum[2] = {0.f, 0.f};

    for (int c0 = start; c0 < end; c0 += 16) {
        int cnt = end - c0; if (cnt > 16) cnt = 16;
        // ---- stage sl -> bf16 LDS (zero-pad partial chunk) ----
#pragma unroll
        for (int i = 0; i < 8; ++i) {
            int idx4 = i * 64 + lane;
            int e = idx4 >> 5, j4 = idx4 & 31;
            float4 v = {0.f, 0.f, 0.f, 0.f};
            if (e < cnt) {
                int ge = csr[c0 + e];
                v = *(const float4*)&sl[(size_t)ge * 128 + j4 * 4];
            }
            short4 s4; s4.x = f2bf(v.x); s4.y = f2bf(v.y); s4.z = f2bf(v.z); s4.w = f2bf(v.w);
            *(short4*)&slb[w][e * 136 + j4 * 4] = s4;
        }
        asm volatile("s_waitcnt lgkmcnt(0)" ::: "memory");
        bf16x8 af[4];
#pragma unroll
        for (int kk = 0; kk < 4; ++kk)
            af[kk] = *(const bf16x8*)&slb[w][r * 136 + kk * 32 + q * 8];

        // ---- logits -> z  (C: row e = q*4+reg, col m = ct*16+r) ----
        float zv[2][4];
#pragma unroll
        for (int ct = 0; ct < 2; ++ct) {
            f32x4 acc = {0.f, 0.f, 0.f, 0.f};
#pragma unroll
            for (int kk = 0; kk < 4; ++kk)
                acc = __builtin_amdgcn_mfma_f32_16x16x32_bf16(af[kk], vb[ct][kk], acc, 0, 0, 0);
#pragma unroll
            for (int reg = 0; reg < 4; ++reg) {
                float l = acc[reg] * 0.25f;            // INV_SQRTD
                l = fminf(5.f, fmaxf(-5.f, l));        // clip
                zv[ct][reg] = __expf(l);
            }
        }

        // ---- g = silu(sl@Wenv + b) -> glds (bf16, row e, col gcol) ----
#pragma unroll
        for (int g4 = 0; g4 < 4; ++g4) {
            f32x4 acc = {0.f, 0.f, 0.f, 0.f};
#pragma unroll
            for (int kk = 0; kk < 4; ++kk) {
                bf16x8 bb = *(const bf16x8*)&WenvT[(g4 * 16 + r) * 128 + kk * 32 + q * 8];
                acc = __builtin_amdgcn_mfma_f32_16x16x32_bf16(af[kk], bb, acc, 0, 0, 0);
            }
#pragma unroll
            for (int reg = 0; reg < 4; ++reg) {
                float x = acc[reg] + bias[g4];
                float gv = x / (1.f + __expf(-x));
                glds[w][(q * 4 + reg) * 68 + g4 * 16 + r] = f2bf(gv);
            }
        }
        asm volatile("s_waitcnt lgkmcnt(0)" ::: "memory");

        // ---- accumulate denom + sum z*g*equiv ----
#pragma unroll
        for (int reg = 0; reg < 4; ++reg) {
            int e = q * 4 + reg;
            if (e < cnt) {
                int ge = csr[c0 + e];
#pragma unroll
                for (int ct = 0; ct < 2; ++ct) {
                    int m = ct * 16 + r;
                    float z = zv[ct][reg];
                    unsigned gp = *(const unsigned*)&glds[w][e * 68 + 2 * m];
                    float g0 = bf2f((short)(gp & 0xFFFFu));
                    float g1 = bf2f((short)(gp >> 16));
                    float4 eq = *(const float4*)&equiv[(size_t)ge * 128 + m * 4];
                    facc[ct][0] += z * g0 * eq.x;
                    facc[ct][1] += z * g1 * eq.y;
                    facc[ct][2] += z * g1 * eq.z;
                    facc[ct][3] += z * g1 * eq.w;
                    dsum[ct] += z;
                }
            }
        }
    }

    // ---- reduce over q (lanes ^16, ^32) ----
#pragma unroll
    for (int off = 16; off < 64; off <<= 1) {
#pragma unroll
        for (int ct = 0; ct < 2; ++ct) {
#pragma unroll
            for (int i = 0; i < 4; ++i) facc[ct][i] += __shfl_xor(facc[ct][i], off, 64);
            dsum[ct] += __shfl_xor(dsum[ct], off, 64);
        }
    }
    float env0[4], env1[4];
    float inv0 = 1.f / dsum[0], inv1 = 1.f / dsum[1];
#pragma unroll
    for (int i = 0; i < 4; ++i) { env0[i] = facc[0][i] * inv0; env1[i] = facc[1][i] * inv1; }
    // SO3 LN: s0 over d=0 comps (32 vals), s1 over d=1..3 (96 vals)
    float p0 = env0[0] * env0[0] + env1[0] * env1[0];
    float p1 = env0[1]*env0[1] + env0[2]*env0[2] + env0[3]*env0[3]
             + env1[1]*env1[1] + env1[2]*env1[2] + env1[3]*env1[3];
#pragma unroll
    for (int off = 1; off < 16; off <<= 1) {
        p0 += __shfl_xor(p0, off, 64);
        p1 += __shfl_xor(p1, off, 64);
    }
    float i0 = rsqrtf(p0 * (1.f / 32.f) + 1e-6f);
    float i1 = rsqrtf(p1 * (1.f / 96.f) + 1e-6f);
    if (q == 0) {
        float4 o0, o1;
        o0.x = env0[0] * i0; o0.y = env0[1] * i1; o0.z = env0[2] * i1; o0.w = env0[3] * i1;
        o1.x = env1[0] * i0; o1.y = env1[1] * i1; o1.z = env1[2] * i1; o1.w = env1[3] * i1;
        *(float4*)&envn[(size_t)node * 128 + r * 4] = o0;
        *(float4*)&envn[(size_t)node * 128 + 64 + r * 4] = o1;
    }
}

// ---------------- final: tp, per-edge LN, feats, mix|sc GEMM, outputs ----------------
__launch_bounds__(256)
__global__ void kfinal(const float* __restrict__ sl, const float* __restrict__ equiv,
                       const float* __restrict__ econd, const int* __restrict__ ec,
                       const float* __restrict__ envn, const short* __restrict__ WcatT,
                       const float* __restrict__ bmix, const float* __restrict__ bsc,
                       const float* __restrict__ ucp, float* __restrict__ out) {
    __shared__ float eqlds[16 * 132];
    __shared__ float envl[16 * 132];
    __shared__ float mixl[16 * 132];
    __shared__ float condl[16 * 16];
    __shared__ short featb[16 * 104];
    __shared__ int cn[16];

    int tid = threadIdx.x;
    int eBase = blockIdx.x * 16;
    if (tid < 16) cn[tid] = ec[eBase + tid];
    for (int idx = tid; idx < 512; idx += 256) {
        int e = idx >> 5, j4 = idx & 31;
        *(float4*)&eqlds[e * 132 + j4 * 4] =
            *(const float4*)&equiv[(size_t)(eBase + e) * 128 + j4 * 4];
    }
    {
        int e = tid >> 4, j = tid & 15;
        condl[tid] = econd[(eBase + e) * 16 + j];
    }
    float uc = ucp[0];
    float c_old = rsqrtf(uc * uc + 1.f);
    float c_new = uc * c_old;
    __syncthreads();
    for (int idx = tid; idx < 512; idx += 256) {
        int e = idx >> 5, j4 = idx & 31;
        *(float4*)&envl[e * 132 + j4 * 4] =
            *(const float4*)&envn[(size_t)cn[e] * 128 + j4 * 4];
    }
    __syncthreads();

    int e = tid >> 4, i = tid & 15;
    float tp[2][8];
    {
        float s0 = 0, s1 = 0, s2 = 0, s3 = 0;
#pragma unroll
        for (int t2 = 0; t2 < 2; ++t2) {
            int m = i * 2 + t2;
            float4 x = *(const float4*)&eqlds[e * 132 + m * 4];
            float4 y = *(const float4*)&envl[e * 132 + m * 4];
            tp[t2][0] = x.x * y.x;
            tp[t2][1] = x.x * y.y; tp[t2][2] = x.x * y.z; tp[t2][3] = x.x * y.w;
            tp[t2][4] = x.y * y.x; tp[t2][5] = x.z * y.x; tp[t2][6] = x.w * y.x;
            tp[t2][7] = (x.y * y.y + x.z * y.z + x.w * y.w) * 0.57735026919f;
            s0 += tp[t2][0] * tp[t2][0];
            s1 += tp[t2][1] * tp[t2][1] + tp[t2][2] * tp[t2][2] + tp[t2][3] * tp[t2][3];
            s2 += tp[t2][4] * tp[t2][4] + tp[t2][5] * tp[t2][5] + tp[t2][6] * tp[t2][6];
            s3 += tp[t2][7] * tp[t2][7];
        }
#pragma unroll
        for (int off = 1; off < 16; off <<= 1) {
            s0 += __shfl_xor(s0, off, 16);
            s1 += __shfl_xor(s1, off, 16);
            s2 += __shfl_xor(s2, off, 16);
            s3 += __shfl_xor(s3, off, 16);
        }
        float i0 = rsqrtf(s0 * (1.f / 32.f) + 1e-6f);
        float i1 = rsqrtf(s1 * (1.f / 96.f) + 1e-6f);
        float i2 = rsqrtf(s2 * (1.f / 96.f) + 1e-6f);
        float i3 = rsqrtf(s3 * (1.f / 32.f) + 1e-6f);
#pragma unroll
        for (int t2 = 0; t2 < 2; ++t2) {
            tp[t2][0] *= i0;
            tp[t2][1] *= i1; tp[t2][2] *= i1; tp[t2][3] *= i1;
            tp[t2][4] *= i2; tp[t2][5] *= i2; tp[t2][6] *= i2;
            tp[t2][7] *= i3;
            int m = i * 2 + t2;
            featb[e * 104 + m] = f2bf(tp[t2][0]);
            featb[e * 104 + 32 + m] = f2bf(tp[t2][7]);
        }
        featb[e * 104 + 64 + i] = f2bf(condl[e * 16 + i]);
        featb[e * 104 + 80 + i] = 0;
    }
    __syncthreads();

    int lane = tid & 63, wv = tid >> 6;
    int r = lane & 15, q = lane >> 4;
    bf16x8 af[3];
#pragma unroll
    for (int kk = 0; kk < 3; ++kk)
        af[kk] = *(const bf16x8*)&featb[r * 104 + kk * 32 + q * 8];
#pragma unroll
    for (int ct4 = 0; ct4 < 4; ++ct4) {
        int ct = wv * 4 + ct4;
        f32x4 acc = {0.f, 0.f, 0.f, 0.f};
#pragma unroll
        for (int kk = 0; kk < 3; ++kk) {
            bf16x8 bb = *(const bf16x8*)&WcatT[(ct * 16 + r) * 96 + kk * 32 + q * 8];
            acc = __builtin_amdgcn_mfma_f32_16x16x32_bf16(af[kk], bb, acc, 0, 0, 0);
        }
        int colg = ct * 16 + r;
        if (colg < 128) {
            float bias = bmix[colg];
#pragma unroll
            for (int reg = 0; reg < 4; ++reg) {
                int ee = q * 4 + reg;
                mixl[ee * 132 + colg] = acc[reg] + bias;
            }
        } else {
            int j = colg - 128;
            float bias = bsc[j];
#pragma unroll
            for (int reg = 0; reg < 4; ++reg) {
                int ee = q * 4 + reg;
                int ge = eBase + ee;
                out[ge * 128 + j] = c_old * sl[ge * 128 + j] + c_new * (acc[reg] + bias);
            }
        }
    }
    __syncthreads();

    float* outeq = out + (size_t)E_EDGES * 128;
#pragma unroll
    for (int t2 = 0; t2 < 2; ++t2) {
        int m = i * 2 + t2;
        float4 mx = *(const float4*)&mixl[e * 132 + m * 4];
        float4 eq = *(const float4*)&eqlds[e * 132 + m * 4];
        float4 o;
        o.x = c_old * eq.x + c_new * (mx.x * tp[t2][0] + mx.y * tp[t2][7]);
        o.y = c_old * eq.y + c_new * (mx.z * tp[t2][1] + mx.w * tp[t2][4]);
        o.z = c_old * eq.z + c_new * (mx.z * tp[t2][2] + mx.w * tp[t2][5]);
        o.w = c_old * eq.w + c_new * (mx.z * tp[t2][3] + mx.w * tp[t2][6]);
        *(float4*)&outeq[(size_t)(eBase + e) * 128 + m * 4] = o;
    }
}

extern "C" void kernel_launch(void* const* d_in, const int* in_sizes, int n_in,
                              void* d_out, int out_size, void* d_ws, size_t ws_size,
                              hipStream_t stream) {
    const float* sl    = (const float*)d_in[0];
    const float* eqv   = (const float*)d_in[1];
    const float* ninv  = (const float*)d_in[2];
    const float* econd = (const float*)d_in[3];
    const float* uc    = (const float*)d_in[4];
    const float* Wenv  = (const float*)d_in[5];
    const float* benv  = (const float*)d_in[6];
    const float* Wq    = (const float*)d_in[7];
    const float* Wk    = (const float*)d_in[8];
    const float* Wmix  = (const float*)d_in[9];
    const float* bmix  = (const float*)d_in[10];
    const float* Wsc   = (const float*)d_in[11];
    const float* bsc   = (const float*)d_in[12];
    const int*   ec    = (const int*)d_in[13];
    float* out = (float*)d_out;

    const int NHALF = N_NODES / 2;   // VT double-pass to stay in ws budget

    float* ws = (float*)d_ws;
    float* Qn    = ws;                                     // N*512 f32
    float* envn  = Qn + (size_t)N_NODES * 512;             // N*128 f32
    short* VT    = (short*)(envn + (size_t)N_NODES * 128); // NHALF*4096 bf16
    short* WenvT = VT + (size_t)NHALF * 4096;              // 64*128
    short* WcatT = WenvT + 8192;                           // 256*96
    short* WkB   = WcatT + 24576;                          // 32*128*32
    int*   deg    = (int*)(WkB + 131072);                  // N
    int*   offs   = deg + N_NODES;                         // N+1
    int*   cursor = offs + N_NODES + 1;                    // N
    int*   csr    = cursor + N_NODES;                      // E

    hipMemsetAsync(deg, 0, (size_t)N_NODES * sizeof(int), stream);

    kprep<<<640, 256, 0, stream>>>(Wk, Wenv, Wmix, Wsc, WenvT, WcatT, WkB);
    khist<<<E_EDGES / 256, 256, 0, stream>>>(ec, deg);
    kscan<<<1, 256, 0, stream>>>(deg, offs, cursor);
    kscat<<<E_EDGES / 256, 256, 0, stream>>>(ec, cursor, csr);
    kqn<<<N_NODES / 8, 256, 0, stream>>>(ninv, Wq, Qn);

    for (int pass = 0; pass < 2; ++pass) {
        int nb0 = pass * NHALF;
        kV<<<NHALF / 16, 256, 0, stream>>>(Qn, WkB, VT, nb0);
        kmain2<<<NHALF / 4, 256, 0, stream>>>(sl, eqv, csr, offs, VT, WenvT, benv, envn, nb0);
    }

    kfinal<<<E_EDGES / 16, 256, 0, stream>>>(sl, eqv, econd, ec, envn, WcatT, bmix, bsc, uc, out);
}

// Round 4
// 857.037 us; speedup vs baseline: 1.7487x; 1.0063x over previous
//
#include <hip/hip_runtime.h>
#include <hip/hip_bf16.h>

#define E_EDGES 262144
#define N_NODES 16384

typedef short bf16x8 __attribute__((ext_vector_type(8)));
typedef float f32x4 __attribute__((ext_vector_type(4)));

static __device__ __forceinline__ short f2bf(float f) {
    union { float f; unsigned u; } v; v.f = f;
    unsigned r = v.u + 0x7FFFu + ((v.u >> 16) & 1u);
    return (short)(r >> 16);
}
static __device__ __forceinline__ float bf2f(short s) {
    union { unsigned u; float f; } v;
    v.u = ((unsigned)(unsigned short)s) << 16;
    return v.f;
}

// ---------------- weight prep: bf16 transposed copies ----------------
// WenvT[c*128+k] = W_env[k*64+c]             (64 x 128)
// WcatT[c*96+k]  = [W_mix | W_sc][k][c]      (256 x 96, k>=80 zero)
// WkB[m][c][dp]  = dp<16 ? Wk[c*512+m*16+dp] : 0   (32 x 128 x 32, K-padded)
__global__ void kprep(const float* __restrict__ Wk, const float* __restrict__ Wenv,
                      const float* __restrict__ Wmix, const float* __restrict__ Wsc,
                      short* __restrict__ WenvT, short* __restrict__ WcatT,
                      short* __restrict__ WkB) {
    int idx = blockIdx.x * 256 + threadIdx.x;
    if (idx < 8192) {
        int c = idx >> 7, k = idx & 127;
        WenvT[idx] = f2bf(Wenv[k * 64 + c]);
    } else if (idx < 8192 + 24576) {
        int o = idx - 8192;
        int c = o / 96, k = o - c * 96;
        float v = 0.f;
        if (k < 80) v = (c < 128) ? Wmix[k * 128 + c] : Wsc[k * 128 + (c - 128)];
        WcatT[o] = f2bf(v);
    } else {
        int o = idx - 32768;
        int m = o >> 12, rest = o & 4095;
        int c = rest >> 5, dp = rest & 31;
        WkB[o] = (dp < 16) ? f2bf(Wk[c * 512 + m * 16 + dp]) : (short)0;
    }
}

// ---------------- CSR build: histogram, scan, scatter ----------------
__global__ void khist(const int* __restrict__ ec, int* __restrict__ deg) {
    int e = blockIdx.x * 256 + threadIdx.x;
    atomicAdd(&deg[ec[e]], 1);
}

__global__ void kscan(const int* __restrict__ deg, int* __restrict__ offs,
                      int* __restrict__ cursor) {
    __shared__ int part[256];
    int t = threadIdx.x;
    int s = 0;
    for (int i = 0; i < 64; ++i) s += deg[t * 64 + i];
    part[t] = s;
    __syncthreads();
    if (t == 0) {
        int acc = 0;
        for (int i = 0; i < 256; ++i) { int v = part[i]; part[i] = acc; acc += v; }
        offs[N_NODES] = acc;
    }
    __syncthreads();
    int p = part[t];
    for (int i = 0; i < 64; ++i) {
        int idx = t * 64 + i;
        offs[idx] = p;
        cursor[idx] = p;
        p += deg[idx];
    }
}

__global__ void kscat(const int* __restrict__ ec, int* __restrict__ cursor,
                      int* __restrict__ csr) {
    int e = blockIdx.x * 256 + threadIdx.x;
    int p = atomicAdd(&cursor[ec[e]], 1);
    csr[p] = e;
}

// ---------------- Qn = node_invariants @ Wq  (N x 512, fp32) ----------------
__global__ void kqn(const float* __restrict__ ninv, const float* __restrict__ Wq,
                    float* __restrict__ Qn) {
    __shared__ float ni[8 * 68];
    int nBase = blockIdx.x * 8;
    int tid = threadIdx.x;
    for (int idx = tid; idx < 512; idx += 256) {
        int n = idx >> 6, j = idx & 63;
        ni[n * 68 + j] = ninv[(nBase + n) * 64 + j];
    }
    __syncthreads();
    float a0[8] = {0,0,0,0,0,0,0,0};
    float a1[8] = {0,0,0,0,0,0,0,0};
    for (int j = 0; j < 64; ++j) {
        float w0 = Wq[j * 512 + tid];
        float w1 = Wq[j * 512 + tid + 256];
#pragma unroll
        for (int n = 0; n < 8; ++n) {
            float s = ni[n * 68 + j];
            a0[n] += s * w0;
            a1[n] += s * w1;
        }
    }
#pragma unroll
    for (int n = 0; n < 8; ++n) {
        Qn[(nBase + n) * 512 + tid] = a0[n];
        Qn[(nBase + n) * 512 + tid + 256] = a1[n];
    }
}

// ---------------- kV: VT[nloc][m][c] = bf16( sum_d Wk[c,m*16+d] * Q[n,m*16+d] ) ----
__launch_bounds__(256)
__global__ void kV(const float* __restrict__ Qn, const short* __restrict__ WkB,
                   short* __restrict__ VT, int nb0) {
    int tid = threadIdx.x;
    int w = tid >> 6, lane = tid & 63;
    int r = lane & 15, q = lane >> 4;
    int nbl = blockIdx.x * 16;
#pragma unroll
    for (int mi = 0; mi < 8; ++mi) {
        int m = w * 8 + mi;
        const float* qp = &Qn[(size_t)(nb0 + nbl + r) * 512 + m * 16 + (q & 1) * 8];
        float4 qa = *(const float4*)qp;
        float4 qb = *(const float4*)(qp + 4);
        bf16x8 af;
        af[0] = f2bf(qa.x); af[1] = f2bf(qa.y); af[2] = f2bf(qa.z); af[3] = f2bf(qa.w);
        af[4] = f2bf(qb.x); af[5] = f2bf(qb.y); af[6] = f2bf(qb.z); af[7] = f2bf(qb.w);
#pragma unroll
        for (int ct = 0; ct < 8; ++ct) {
            bf16x8 bb = *(const bf16x8*)&WkB[(m * 128 + ct * 16 + r) * 32 + q * 8];
            f32x4 acc = {0.f, 0.f, 0.f, 0.f};
            acc = __builtin_amdgcn_mfma_f32_16x16x32_bf16(af, bb, acc, 0, 0, 0);
#pragma unroll
            for (int reg = 0; reg < 4; ++reg) {
                VT[(size_t)(nbl + q * 4 + reg) * 4096 + m * 128 + ct * 16 + r] =
                    f2bf(acc[reg]);
            }
        }
    }
}

// ---------------- kmain2: per-node fused logits/g/attn-aggregate/LN ----------------
__launch_bounds__(256)
__global__ void kmain2(const float* __restrict__ sl, const float* __restrict__ equiv,
                       const int* __restrict__ csr, const int* __restrict__ offs,
                       const short* __restrict__ VT, const short* __restrict__ WenvT,
                       const float* __restrict__ benv, float* __restrict__ envn,
                       int nb0) {
    __shared__ short slb[4][16 * 136];
    __shared__ short glds[4][16 * 68];
    int tid = threadIdx.x;
    int w = tid >> 6, lane = tid & 63;
    int r = lane & 15, q = lane >> 4;
    int node = nb0 + blockIdx.x * 4 + w;
    int start = offs[node], end = offs[node + 1];
    if (start >= end) return;   // no barriers in this kernel -> per-wave return is safe

    bf16x8 vb[2][4];
    const short* vtn = VT + (size_t)(node - nb0) * 4096;
#pragma unroll
    for (int ct = 0; ct < 2; ++ct)
#pragma unroll
        for (int kk = 0; kk < 4; ++kk)
            vb[ct][kk] = *(const bf16x8*)&vtn[(ct * 16 + r) * 128 + kk * 32 + q * 8];
    float bias[4];
#pragma unroll
    for (int g4 = 0; g4 < 4; ++g4) bias[g4] = benv[g4 * 16 + r];

    float facc[2][4] = {{0,0,0,0},{0,0,0,0}};
    float dsum[2] = {0.f, 0.f};

    for (int c0 = start; c0 < end; c0 += 16) {
        int cnt = end - c0; if (cnt > 16) cnt = 16;
#pragma unroll
        for (int i = 0; i < 8; ++i) {
            int idx4 = i * 64 + lane;
            int e = idx4 >> 5, j4 = idx4 & 31;
            float4 v = {0.f, 0.f, 0.f, 0.f};
            if (e < cnt) {
                int ge = csr[c0 + e];
                v = *(const float4*)&sl[(size_t)ge * 128 + j4 * 4];
            }
            short4 s4; s4.x = f2bf(v.x); s4.y = f2bf(v.y); s4.z = f2bf(v.z); s4.w = f2bf(v.w);
            *(short4*)&slb[w][e * 136 + j4 * 4] = s4;
        }
        asm volatile("s_waitcnt lgkmcnt(0)" ::: "memory");
        bf16x8 af[4];
#pragma unroll
        for (int kk = 0; kk < 4; ++kk)
            af[kk] = *(const bf16x8*)&slb[w][r * 136 + kk * 32 + q * 8];

        float zv[2][4];
#pragma unroll
        for (int ct = 0; ct < 2; ++ct) {
            f32x4 acc = {0.f, 0.f, 0.f, 0.f};
#pragma unroll
            for (int kk = 0; kk < 4; ++kk)
                acc = __builtin_amdgcn_mfma_f32_16x16x32_bf16(af[kk], vb[ct][kk], acc, 0, 0, 0);
#pragma unroll
            for (int reg = 0; reg < 4; ++reg) {
                float l = acc[reg] * 0.25f;            // INV_SQRTD
                l = fminf(5.f, fmaxf(-5.f, l));        // clip
                zv[ct][reg] = __expf(l);
            }
        }

#pragma unroll
        for (int g4 = 0; g4 < 4; ++g4) {
            f32x4 acc = {0.f, 0.f, 0.f, 0.f};
#pragma unroll
            for (int kk = 0; kk < 4; ++kk) {
                bf16x8 bb = *(const bf16x8*)&WenvT[(g4 * 16 + r) * 128 + kk * 32 + q * 8];
                acc = __builtin_amdgcn_mfma_f32_16x16x32_bf16(af[kk], bb, acc, 0, 0, 0);
            }
#pragma unroll
            for (int reg = 0; reg < 4; ++reg) {
                float x = acc[reg] + bias[g4];
                float gv = x / (1.f + __expf(-x));
                glds[w][(q * 4 + reg) * 68 + g4 * 16 + r] = f2bf(gv);
            }
        }
        asm volatile("s_waitcnt lgkmcnt(0)" ::: "memory");

#pragma unroll
        for (int reg = 0; reg < 4; ++reg) {
            int e = q * 4 + reg;
            if (e < cnt) {
                int ge = csr[c0 + e];
#pragma unroll
                for (int ct = 0; ct < 2; ++ct) {
                    int m = ct * 16 + r;
                    float z = zv[ct][reg];
                    unsigned gp = *(const unsigned*)&glds[w][e * 68 + 2 * m];
                    float g0 = bf2f((short)(gp & 0xFFFFu));
                    float g1 = bf2f((short)(gp >> 16));
                    float4 eq = *(const float4*)&equiv[(size_t)ge * 128 + m * 4];
                    facc[ct][0] += z * g0 * eq.x;
                    facc[ct][1] += z * g1 * eq.y;
                    facc[ct][2] += z * g1 * eq.z;
                    facc[ct][3] += z * g1 * eq.w;
                    dsum[ct] += z;
                }
            }
        }
    }

#pragma unroll
    for (int off = 16; off < 64; off <<= 1) {
#pragma unroll
        for (int ct = 0; ct < 2; ++ct) {
#pragma unroll
            for (int i = 0; i < 4; ++i) facc[ct][i] += __shfl_xor(facc[ct][i], off, 64);
            dsum[ct] += __shfl_xor(dsum[ct], off, 64);
        }
    }
    float env0[4], env1[4];
    float inv0 = 1.f / dsum[0], inv1 = 1.f / dsum[1];
#pragma unroll
    for (int i = 0; i < 4; ++i) { env0[i] = facc[0][i] * inv0; env1[i] = facc[1][i] * inv1; }
    float p0 = env0[0] * env0[0] + env1[0] * env1[0];
    float p1 = env0[1]*env0[1] + env0[2]*env0[2] + env0[3]*env0[3]
             + env1[1]*env1[1] + env1[2]*env1[2] + env1[3]*env1[3];
#pragma unroll
    for (int off = 1; off < 16; off <<= 1) {
        p0 += __shfl_xor(p0, off, 64);
        p1 += __shfl_xor(p1, off, 64);
    }
    float i0 = rsqrtf(p0 * (1.f / 32.f) + 1e-6f);
    float i1 = rsqrtf(p1 * (1.f / 96.f) + 1e-6f);
    if (q == 0) {
        float4 o0, o1;
        o0.x = env0[0] * i0; o0.y = env0[1] * i1; o0.z = env0[2] * i1; o0.w = env0[3] * i1;
        o1.x = env1[0] * i0; o1.y = env1[1] * i1; o1.z = env1[2] * i1; o1.w = env1[3] * i1;
        *(float4*)&envn[(size_t)node * 128 + r * 4] = o0;
        *(float4*)&envn[(size_t)node * 128 + 64 + r * 4] = o1;
    }
}

// ---------------- final: tp, per-edge LN, feats, mix|sc GEMM, outputs ----------------
// Slimmed LDS (only featb + mixl): direct register loads for equiv/envn/econd/ec,
// 2 barriers. LDS 11.9 KB -> occupancy capped by 32 waves/CU, not LDS.
__launch_bounds__(256)
__global__ void kfinal(const float* __restrict__ sl, const float* __restrict__ equiv,
                       const float* __restrict__ econd, const int* __restrict__ ec,
                       const float* __restrict__ envn, const short* __restrict__ WcatT,
                       const float* __restrict__ bmix, const float* __restrict__ bsc,
                       const float* __restrict__ ucp, float* __restrict__ out) {
    __shared__ float mixl[16 * 132];
    __shared__ short featb[16 * 104];

    int tid = threadIdx.x;
    int eBase = blockIdx.x * 16;
    int e = tid >> 4, i = tid & 15;
    int ge = eBase + e;

    float uc = ucp[0];
    float c_old = rsqrtf(uc * uc + 1.f);
    float c_new = uc * c_old;

    // direct loads in consuming layout (all coalesced; ec is a 16-lane broadcast)
    int cnode = ec[ge];
    float4 x0 = *(const float4*)&equiv[(size_t)ge * 128 + (i * 2) * 4];
    float4 x1 = *(const float4*)&equiv[(size_t)ge * 128 + (i * 2 + 1) * 4];
    float4 y0 = *(const float4*)&envn[(size_t)cnode * 128 + (i * 2) * 4];
    float4 y1 = *(const float4*)&envn[(size_t)cnode * 128 + (i * 2 + 1) * 4];
    float cond = econd[(size_t)eBase * 16 + tid];

    // ---- phase 1: tensor product + per-edge SO3 LN -> featb ----
    float tp[2][8];
    {
        float s0, s1, s2, s3;
        {
            tp[0][0] = x0.x * y0.x;
            tp[0][1] = x0.x * y0.y; tp[0][2] = x0.x * y0.z; tp[0][3] = x0.x * y0.w;
            tp[0][4] = x0.y * y0.x; tp[0][5] = x0.z * y0.x; tp[0][6] = x0.w * y0.x;
            tp[0][7] = (x0.y * y0.y + x0.z * y0.z + x0.w * y0.w) * 0.57735026919f;
            tp[1][0] = x1.x * y1.x;
            tp[1][1] = x1.x * y1.y; tp[1][2] = x1.x * y1.z; tp[1][3] = x1.x * y1.w;
            tp[1][4] = x1.y * y1.x; tp[1][5] = x1.z * y1.x; tp[1][6] = x1.w * y1.x;
            tp[1][7] = (x1.y * y1.y + x1.z * y1.z + x1.w * y1.w) * 0.57735026919f;
            s0 = tp[0][0] * tp[0][0] + tp[1][0] * tp[1][0];
            s1 = tp[0][1] * tp[0][1] + tp[0][2] * tp[0][2] + tp[0][3] * tp[0][3]
               + tp[1][1] * tp[1][1] + tp[1][2] * tp[1][2] + tp[1][3] * tp[1][3];
            s2 = tp[0][4] * tp[0][4] + tp[0][5] * tp[0][5] + tp[0][6] * tp[0][6]
               + tp[1][4] * tp[1][4] + tp[1][5] * tp[1][5] + tp[1][6] * tp[1][6];
            s3 = tp[0][7] * tp[0][7] + tp[1][7] * tp[1][7];
        }
#pragma unroll
        for (int off = 1; off < 16; off <<= 1) {
            s0 += __shfl_xor(s0, off, 16);
            s1 += __shfl_xor(s1, off, 16);
            s2 += __shfl_xor(s2, off, 16);
            s3 += __shfl_xor(s3, off, 16);
        }
        float i0 = rsqrtf(s0 * (1.f / 32.f) + 1e-6f);
        float i1 = rsqrtf(s1 * (1.f / 96.f) + 1e-6f);
        float i2 = rsqrtf(s2 * (1.f / 96.f) + 1e-6f);
        float i3 = rsqrtf(s3 * (1.f / 32.f) + 1e-6f);
#pragma unroll
        for (int t2 = 0; t2 < 2; ++t2) {
            tp[t2][0] *= i0;
            tp[t2][1] *= i1; tp[t2][2] *= i1; tp[t2][3] *= i1;
            tp[t2][4] *= i2; tp[t2][5] *= i2; tp[t2][6] *= i2;
            tp[t2][7] *= i3;
            int m = i * 2 + t2;
            featb[e * 104 + m] = f2bf(tp[t2][0]);
            featb[e * 104 + 32 + m] = f2bf(tp[t2][7]);
        }
        featb[e * 104 + 64 + i] = f2bf(cond);
        featb[e * 104 + 80 + i] = 0;
    }
    __syncthreads();

    // ---- phase 2: [mix | new_scalar] = feats @ WcatT (K=96), MFMA ----
    {
        int lane = tid & 63, wv = tid >> 6;
        int r = lane & 15, q = lane >> 4;
        bf16x8 af[3];
#pragma unroll
        for (int kk = 0; kk < 3; ++kk)
            af[kk] = *(const bf16x8*)&featb[r * 104 + kk * 32 + q * 8];
#pragma unroll
        for (int ct4 = 0; ct4 < 4; ++ct4) {
            int ct = wv * 4 + ct4;
            f32x4 acc = {0.f, 0.f, 0.f, 0.f};
#pragma unroll
            for (int kk = 0; kk < 3; ++kk) {
                bf16x8 bb = *(const bf16x8*)&WcatT[(ct * 16 + r) * 96 + kk * 32 + q * 8];
                acc = __builtin_amdgcn_mfma_f32_16x16x32_bf16(af[kk], bb, acc, 0, 0, 0);
            }
            int colg = ct * 16 + r;
            if (colg < 128) {
                float bias = bmix[colg];
#pragma unroll
                for (int reg = 0; reg < 4; ++reg) {
                    int ee = q * 4 + reg;
                    mixl[ee * 132 + colg] = acc[reg] + bias;
                }
            } else {
                int j = colg - 128;
                float bias = bsc[j];
#pragma unroll
                for (int reg = 0; reg < 4; ++reg) {
                    int ee = q * 4 + reg;
                    int g2 = eBase + ee;
                    out[g2 * 128 + j] = c_old * sl[g2 * 128 + j] + c_new * (acc[reg] + bias);
                }
            }
        }
    }
    __syncthreads();

    // ---- phase 3: new_equiv + residual (x0/x1, tp retained in registers) ----
    float* outeq = out + (size_t)E_EDGES * 128;
    {
        float4 mx0 = *(const float4*)&mixl[e * 132 + (i * 2) * 4];
        float4 mx1 = *(const float4*)&mixl[e * 132 + (i * 2 + 1) * 4];
        float4 o0, o1;
        o0.x = c_old * x0.x + c_new * (mx0.x * tp[0][0] + mx0.y * tp[0][7]);
        o0.y = c_old * x0.y + c_new * (mx0.z * tp[0][1] + mx0.w * tp[0][4]);
        o0.z = c_old * x0.z + c_new * (mx0.z * tp[0][2] + mx0.w * tp[0][5]);
        o0.w = c_old * x0.w + c_new * (mx0.z * tp[0][3] + mx0.w * tp[0][6]);
        o1.x = c_old * x1.x + c_new * (mx1.x * tp[1][0] + mx1.y * tp[1][7]);
        o1.y = c_old * x1.y + c_new * (mx1.z * tp[1][1] + mx1.w * tp[1][4]);
        o1.z = c_old * x1.z + c_new * (mx1.z * tp[1][2] + mx1.w * tp[1][5]);
        o1.w = c_old * x1.w + c_new * (mx1.z * tp[1][3] + mx1.w * tp[1][6]);
        *(float4*)&outeq[(size_t)ge * 128 + (i * 2) * 4] = o0;
        *(float4*)&outeq[(size_t)ge * 128 + (i * 2 + 1) * 4] = o1;
    }
}

extern "C" void kernel_launch(void* const* d_in, const int* in_sizes, int n_in,
                              void* d_out, int out_size, void* d_ws, size_t ws_size,
                              hipStream_t stream) {
    const float* sl    = (const float*)d_in[0];
    const float* eqv   = (const float*)d_in[1];
    const float* ninv  = (const float*)d_in[2];
    const float* econd = (const float*)d_in[3];
    const float* uc    = (const float*)d_in[4];
    const float* Wenv  = (const float*)d_in[5];
    const float* benv  = (const float*)d_in[6];
    const float* Wq    = (const float*)d_in[7];
    const float* Wk    = (const float*)d_in[8];
    const float* Wmix  = (const float*)d_in[9];
    const float* bmix  = (const float*)d_in[10];
    const float* Wsc   = (const float*)d_in[11];
    const float* bsc   = (const float*)d_in[12];
    const int*   ec    = (const int*)d_in[13];
    float* out = (float*)d_out;

    const int NHALF = N_NODES / 2;   // VT double-pass to stay in ws budget

    float* ws = (float*)d_ws;
    float* Qn    = ws;                                     // N*512 f32
    float* envn  = Qn + (size_t)N_NODES * 512;             // N*128 f32
    short* VT    = (short*)(envn + (size_t)N_NODES * 128); // NHALF*4096 bf16
    short* WenvT = VT + (size_t)NHALF * 4096;              // 64*128
    short* WcatT = WenvT + 8192;                           // 256*96
    short* WkB   = WcatT + 24576;                          // 32*128*32
    int*   deg    = (int*)(WkB + 131072);                  // N
    int*   offs   = deg + N_NODES;                         // N+1
    int*   cursor = offs + N_NODES + 1;                    // N
    int*   csr    = cursor + N_NODES;                      // E

    hipMemsetAsync(deg, 0, (size_t)N_NODES * sizeof(int), stream);
    hipMemsetAsync(envn, 0, (size_t)N_NODES * 128 * sizeof(float), stream);

    kprep<<<640, 256, 0, stream>>>(Wk, Wenv, Wmix, Wsc, WenvT, WcatT, WkB);
    khist<<<E_EDGES / 256, 256, 0, stream>>>(ec, deg);
    kscan<<<1, 256, 0, stream>>>(deg, offs, cursor);
    kscat<<<E_EDGES / 256, 256, 0, stream>>>(ec, cursor, csr);
    kqn<<<N_NODES / 8, 256, 0, stream>>>(ninv, Wq, Qn);

    for (int pass = 0; pass < 2; ++pass) {
        int nb0 = pass * NHALF;
        kV<<<NHALF / 16, 256, 0, stream>>>(Qn, WkB, VT, nb0);
        kmain2<<<NHALF / 4, 256, 0, stream>>>(sl, eqv, csr, offs, VT, WenvT, benv, envn, nb0);
    }

    kfinal<<<E_EDGES / 16, 256, 0, stream>>>(sl, eqv, econd, ec, envn, WcatT, bmix, bsc, uc, out);
}